// Round 2
// baseline (451.345 us; speedup 1.0000x reference)
//
#include <hip/hip_runtime.h>

typedef __attribute__((ext_vector_type(8))) short s16x8;      // 8 bf16 (4 VGPRs) - MFMA A/B frag
typedef __attribute__((ext_vector_type(8))) unsigned short u16x8;
typedef __attribute__((ext_vector_type(4))) float f32x4;      // MFMA C/D frag

#define B_   64
#define N_   1024
#define CIN_ 16
#define CH_  64
#define CO_  32

// round-to-nearest-even fp32 -> bf16 bits
__device__ __forceinline__ unsigned short f2bf(float f){
  unsigned int u = __float_as_uint(f);
  u += 0x7fffu + ((u >> 16) & 1u);
  return (unsigned short)(u >> 16);
}

// ---------------------------------------------------------------------------
// linear1: H1T[b][h][n] = bf16( x[b,n,:] @ W1[h,:] + b1[h] )   (transposed store)
// one wave per 64 rows, lane = n (perfectly coalesced 128B stores per h)
// ---------------------------------------------------------------------------
__global__ __launch_bounds__(256) void k_linear1(
    const float* __restrict__ x, const float* __restrict__ W1,
    const float* __restrict__ b1, unsigned short* __restrict__ H1T){
  int gt   = blockIdx.x * 256 + threadIdx.x;
  int wave = gt >> 6;           // 1024 waves total
  int lane = gt & 63;
  int b    = wave >> 4;         // 16 waves per batch
  int nl0  = (wave & 15) << 6;  // row offset within batch

  const float4* xv = (const float4*)(x + ((size_t)(b * N_ + nl0 + lane)) * CIN_);
  float xr[16];
#pragma unroll
  for (int i = 0; i < 4; ++i){
    float4 v = xv[i];
    xr[i*4+0] = v.x; xr[i*4+1] = v.y; xr[i*4+2] = v.z; xr[i*4+3] = v.w;
  }
  for (int h = 0; h < CH_; ++h){
    float acc = b1[h];
#pragma unroll
    for (int c = 0; c < CIN_; ++c) acc += xr[c] * W1[h * CIN_ + c];
    H1T[((size_t)(b * CH_ + h)) * N_ + nl0 + lane] = f2bf(acc);
  }
}

// ---------------------------------------------------------------------------
// prop1: per 64-row tile of one batch:
//   C = (graph+I)[rows, :] @ H1  (bf16 MFMA, K=1024), deg accumulated in staging
//   H2 = relu(C * 1/deg)  ->  O1 = H2 @ W2^T + b2 (fused MFMA)  -> O1T bf16
// Register double-buffer: K-step ks+1's global loads issue before ks's
// process/store, so HBM latency overlaps the stage+barrier+MFMA window.
// ---------------------------------------------------------------------------
__global__ __launch_bounds__(256) void k_prop1(
    const float* __restrict__ graph, const unsigned short* __restrict__ H1T,
    const float* __restrict__ W2, const float* __restrict__ b2,
    unsigned short* __restrict__ O1T, float* __restrict__ idegw){
  __shared__ unsigned short sA[64 * 64];   // A tile [row][k]  bf16, XOR-swizzled
  __shared__ unsigned short sB[64 * 64];   // B tile [col][k]  bf16, XOR-swizzled
  __shared__ unsigned short sH2[64 * 64];  // H2    [row][ch]  bf16, XOR-swizzled
  __shared__ float sDegP[4 * 64];
  __shared__ float sIdeg[64];

  const int b    = blockIdx.x >> 4;
  const int mblk = blockIdx.x & 15;
  const int m0   = mblk << 6;
  const int tid  = threadIdx.x;
  const int lane = tid & 63, w = tid >> 6;
  const int l15  = lane & 15, lk = lane >> 4;
  const int srow = tid >> 2,  kq = tid & 3;    // staging: row 0..63, 16 elems each
  const int gn   = m0 + srow;
  const int swzS = (srow & 7) << 3;            // staging swizzle (element units)
  const int swzF = (l15  & 7) << 3;            // frag-read swizzle

  const float*          gRow = graph + ((size_t)b << 20) + ((size_t)gn << 10) + (kq << 4);
  const unsigned short* hRow = H1T + ((size_t)(b * CH_ + srow)) * N_ + (kq << 4);

  float degp = 0.f;
  f32x4 acc[4] = {{0,0,0,0},{0,0,0,0},{0,0,0,0},{0,0,0,0}};

  // prefetch ks=0
  float4 pg[4]; u16x8 ph[2];
  {
    const float4* gp = (const float4*)gRow;
#pragma unroll
    for (int i = 0; i < 4; ++i) pg[i] = gp[i];
    const u16x8* hp = (const u16x8*)hRow;
    ph[0] = hp[0]; ph[1] = hp[1];
  }

  for (int ks = 0; ks < 16; ++ks){
    // ---- issue next step's loads first (latency overlaps this whole step) ----
    float4 ng[4]; u16x8 nh[2];
    if (ks < 15){
      const float4* gp = (const float4*)(gRow + ((ks + 1) << 6));
#pragma unroll
      for (int i = 0; i < 4; ++i) ng[i] = gp[i];
      const u16x8* hp = (const u16x8*)(hRow + ((ks + 1) << 6));
      nh[0] = hp[0]; nh[1] = hp[1];
    } else {
#pragma unroll
      for (int i = 0; i < 4; ++i) ng[i] = pg[i];
      nh[0] = ph[0]; nh[1] = ph[1];
    }

    // ---- stage A: 16 fp32 -> bf16 (+I on diag), accumulate deg ----
    float vals[16];
#pragma unroll
    for (int i = 0; i < 4; ++i){
      float4 v = pg[i];
      if (ks == mblk){                       // diag block only (uniform branch)
        int gc = (ks << 6) + (kq << 4) + (i << 2);
        v.x += (gc + 0 == gn) ? 1.f : 0.f;
        v.y += (gc + 1 == gn) ? 1.f : 0.f;
        v.z += (gc + 2 == gn) ? 1.f : 0.f;
        v.w += (gc + 3 == gn) ? 1.f : 0.f;
      }
      degp += (v.x + v.y) + (v.z + v.w);
      vals[i*4+0] = v.x; vals[i*4+1] = v.y; vals[i*4+2] = v.z; vals[i*4+3] = v.w;
    }
    u16x8 pk0, pk1;
#pragma unroll
    for (int e = 0; e < 8; ++e){ pk0[e] = f2bf(vals[e]); pk1[e] = f2bf(vals[8 + e]); }
    *(u16x8*)&sA[srow * 64 + (((kq << 4) + 0) ^ swzS)] = pk0;
    *(u16x8*)&sA[srow * 64 + (((kq << 4) + 8) ^ swzS)] = pk1;
    // ---- stage B: copy H1T tile (bf16) ----
    *(u16x8*)&sB[srow * 64 + (((kq << 4) + 0) ^ swzS)] = ph[0];
    *(u16x8*)&sB[srow * 64 + (((kq << 4) + 8) ^ swzS)] = ph[1];
    __syncthreads();
    // ---- MFMA: wave w owns rows w*16..+15, cols 0..63 (4 col-frags) ----
#pragma unroll
    for (int kk = 0; kk < 2; ++kk){
      int ko = (kk << 5) + (lk << 3);
      s16x8 a = *(const s16x8*)&sA[((w << 4) + l15) * 64 + (ko ^ swzF)];
#pragma unroll
      for (int cf = 0; cf < 4; ++cf){
        s16x8 bb = *(const s16x8*)&sB[((cf << 4) + l15) * 64 + (ko ^ swzF)];
        acc[cf] = __builtin_amdgcn_mfma_f32_16x16x32_bf16(a, bb, acc[cf], 0, 0, 0);
      }
    }
    __syncthreads();
#pragma unroll
    for (int i = 0; i < 4; ++i) pg[i] = ng[i];
    ph[0] = nh[0]; ph[1] = nh[1];
  }

  // ---- deg reduce -> 1/deg (deg >= 1 always: uniform[0,1) sums + self-loop) ----
  sDegP[(kq << 6) + srow] = degp;
  __syncthreads();
  if (tid < 64){
    float d  = sDegP[tid] + sDegP[64 + tid] + sDegP[128 + tid] + sDegP[192 + tid];
    float id = 1.f / d;
    sIdeg[tid] = id;
    idegw[(b << 10) + m0 + tid] = id;
  }
  __syncthreads();

  // ---- scale + relu -> H2 in LDS (bf16, A-frag-readable layout) ----
  f32x4 idv = *(const f32x4*)&sIdeg[(w << 4) + (lk << 2)];
#pragma unroll
  for (int cf = 0; cf < 4; ++cf){
#pragma unroll
    for (int j = 0; j < 4; ++j){
      float hv = acc[cf][j] * idv[j];
      hv = hv > 0.f ? hv : 0.f;
      int row = (w << 4) + (lk << 2) + j;
      int col = (cf << 4) + l15;
      sH2[row * 64 + (col ^ ((row & 7) << 3))] = f2bf(hv);
    }
  }
  __syncthreads();

  // ---- fused linear2: O1[16x32] = H2[16x64] @ W2^T + b2 ----
  f32x4 acc2[2] = {{0,0,0,0},{0,0,0,0}};
#pragma unroll
  for (int kk = 0; kk < 2; ++kk){
    int ko = (kk << 5) + (lk << 3);
    s16x8 a2 = *(const s16x8*)&sH2[((w << 4) + l15) * 64 + (ko ^ swzF)];
#pragma unroll
    for (int cf = 0; cf < 2; ++cf){
      const float4* wv = (const float4*)(W2 + ((cf << 4) + l15) * CH_ + ko);
      float4 w0 = wv[0], w1 = wv[1];
      s16x8 bw;
      bw[0] = (short)f2bf(w0.x); bw[1] = (short)f2bf(w0.y);
      bw[2] = (short)f2bf(w0.z); bw[3] = (short)f2bf(w0.w);
      bw[4] = (short)f2bf(w1.x); bw[5] = (short)f2bf(w1.y);
      bw[6] = (short)f2bf(w1.z); bw[7] = (short)f2bf(w1.w);
      acc2[cf] = __builtin_amdgcn_mfma_f32_16x16x32_bf16(a2, bw, acc2[cf], 0, 0, 0);
    }
  }
#pragma unroll
  for (int cf = 0; cf < 2; ++cf){
    float badd = b2[(cf << 4) + l15];
#pragma unroll
    for (int j = 0; j < 4; ++j){
      float v = acc2[cf][j] + badd;          // NO relu here (relu after prop2)
      int n = m0 + (w << 4) + (lk << 2) + j;
      O1T[((size_t)(b * CO_ + (cf << 4) + l15)) * N_ + n] = f2bf(v);
    }
  }
}

// ---------------------------------------------------------------------------
// prop2: out = relu( 1/deg * (graph+I) @ O1 )   (reads stored inv_deg)
// ---------------------------------------------------------------------------
__global__ __launch_bounds__(256) void k_prop2(
    const float* __restrict__ graph, const unsigned short* __restrict__ O1T,
    const float* __restrict__ idegw, float* __restrict__ out){
  __shared__ unsigned short sA[64 * 64];
  __shared__ unsigned short sB[32 * 64];
  __shared__ float sIdeg[64];

  const int b    = blockIdx.x >> 4;
  const int mblk = blockIdx.x & 15;
  const int m0   = mblk << 6;
  const int tid  = threadIdx.x;
  const int lane = tid & 63, w = tid >> 6;
  const int l15  = lane & 15, lk = lane >> 4;
  const int srow = tid >> 2,  kq = tid & 3;
  const int gn   = m0 + srow;
  const int swzS = (srow & 7) << 3;
  const int swzF = (l15  & 7) << 3;

  if (tid < 64) sIdeg[tid] = idegw[(b << 10) + m0 + tid];

  const float* gRow = graph + ((size_t)b << 20) + ((size_t)gn << 10) + (kq << 4);
  const int bcolS = tid >> 3, bkq = tid & 7;   // B staging: 32 cols x 8 chunks
  const unsigned short* oRow = O1T + ((size_t)(b * CO_ + bcolS)) * N_ + (bkq << 3);
  const int swzB = (bcolS & 7) << 3;

  f32x4 acc[2] = {{0,0,0,0},{0,0,0,0}};

  // prefetch ks=0
  float4 pg[4]; u16x8 po;
  {
    const float4* gp = (const float4*)gRow;
#pragma unroll
    for (int i = 0; i < 4; ++i) pg[i] = gp[i];
    po = *(const u16x8*)oRow;
  }

  for (int ks = 0; ks < 16; ++ks){
    float4 ng[4]; u16x8 no;
    if (ks < 15){
      const float4* gp = (const float4*)(gRow + ((ks + 1) << 6));
#pragma unroll
      for (int i = 0; i < 4; ++i) ng[i] = gp[i];
      no = *(const u16x8*)(oRow + ((ks + 1) << 6));
    } else {
#pragma unroll
      for (int i = 0; i < 4; ++i) ng[i] = pg[i];
      no = po;
    }

    float vals[16];
#pragma unroll
    for (int i = 0; i < 4; ++i){
      float4 v = pg[i];
      if (ks == mblk){
        int gc = (ks << 6) + (kq << 4) + (i << 2);
        v.x += (gc + 0 == gn) ? 1.f : 0.f;
        v.y += (gc + 1 == gn) ? 1.f : 0.f;
        v.z += (gc + 2 == gn) ? 1.f : 0.f;
        v.w += (gc + 3 == gn) ? 1.f : 0.f;
      }
      vals[i*4+0] = v.x; vals[i*4+1] = v.y; vals[i*4+2] = v.z; vals[i*4+3] = v.w;
    }
    u16x8 pk0, pk1;
#pragma unroll
    for (int e = 0; e < 8; ++e){ pk0[e] = f2bf(vals[e]); pk1[e] = f2bf(vals[8 + e]); }
    *(u16x8*)&sA[srow * 64 + (((kq << 4) + 0) ^ swzS)] = pk0;
    *(u16x8*)&sA[srow * 64 + (((kq << 4) + 8) ^ swzS)] = pk1;
    *(u16x8*)&sB[bcolS * 64 + ((bkq << 3) ^ swzB)] = po;
    __syncthreads();
#pragma unroll
    for (int kk = 0; kk < 2; ++kk){
      int ko = (kk << 5) + (lk << 3);
      s16x8 a = *(const s16x8*)&sA[((w << 4) + l15) * 64 + (ko ^ swzF)];
#pragma unroll
      for (int cf = 0; cf < 2; ++cf){
        s16x8 bb = *(const s16x8*)&sB[((cf << 4) + l15) * 64 + (ko ^ swzF)];
        acc[cf] = __builtin_amdgcn_mfma_f32_16x16x32_bf16(a, bb, acc[cf], 0, 0, 0);
      }
    }
    __syncthreads();
#pragma unroll
    for (int i = 0; i < 4; ++i) pg[i] = ng[i];
    po = no;
  }

  f32x4 idv = *(const f32x4*)&sIdeg[(w << 4) + (lk << 2)];
#pragma unroll
  for (int cf = 0; cf < 2; ++cf){
#pragma unroll
    for (int j = 0; j < 4; ++j){
      float v = acc[cf][j] * idv[j];
      v = v > 0.f ? v : 0.f;
      int n = m0 + (w << 4) + (lk << 2) + j;
      out[((size_t)(b * N_ + n)) * CO_ + (cf << 4) + l15] = v;
    }
  }
}

// ---------------------------------------------------------------------------
extern "C" void kernel_launch(void* const* d_in, const int* in_sizes, int n_in,
                              void* d_out, int out_size, void* d_ws, size_t ws_size,
                              hipStream_t stream){
  (void)in_sizes; (void)n_in; (void)out_size; (void)ws_size;
  const float* x     = (const float*)d_in[0];
  const float* graph = (const float*)d_in[1];
  const float* W1    = (const float*)d_in[2];
  const float* b1    = (const float*)d_in[3];
  const float* W2    = (const float*)d_in[4];
  const float* b2    = (const float*)d_in[5];
  float* out = (float*)d_out;

  // ws layout: H1T bf16 [64][64][1024] = 8MB | O1T bf16 [64][32][1024] = 4MB | ideg f32 = 256KB
  unsigned short* H1T = (unsigned short*)d_ws;
  unsigned short* O1T = (unsigned short*)((char*)d_ws + ((size_t)8 << 20));
  float*        idegw = (float*)((char*)d_ws + ((size_t)12 << 20));

  k_linear1<<<256, 256, 0, stream>>>(x, W1, b1, H1T);
  k_prop1<<<B_ * 16, 256, 0, stream>>>(graph, H1T, W2, b2, O1T, idegw);
  k_prop2<<<B_ * 16, 256, 0, stream>>>(graph, O1T, idegw, out);
}